// Round 1
// baseline (356.481 us; speedup 1.0000x reference)
//
#include <hip/hip_runtime.h>

#define N_NODES 16384
#define N_EDGES 8192
#define MAXD 32

// ---------------- pass 1: scan dense H -> edge member lists + node counts ----------------
__global__ __launch_bounds__(256) void scan_H_k(const float* __restrict__ H,
    int* __restrict__ edge_cnt, int* __restrict__ edge_nodes, int* __restrict__ node_cnt)
{
    const unsigned total4 = (unsigned)N_NODES * (N_EDGES / 4);
    for (unsigned i = blockIdx.x * blockDim.x + threadIdx.x; i < total4;
         i += gridDim.x * blockDim.x) {
        float4 x = reinterpret_cast<const float4*>(H)[i];
        if (x.x != 0.f || x.y != 0.f || x.z != 0.f || x.w != 0.f) {
            unsigned base = i * 4u;
            int n  = (int)(base >> 13);          // /N_EDGES
            int e0 = (int)(base & (N_EDGES - 1));
            int c = 0;
            if (x.x != 0.f) { int p = atomicAdd(&edge_cnt[e0+0], 1); if (p < MAXD) edge_nodes[(e0+0)*MAXD+p] = n; c++; }
            if (x.y != 0.f) { int p = atomicAdd(&edge_cnt[e0+1], 1); if (p < MAXD) edge_nodes[(e0+1)*MAXD+p] = n; c++; }
            if (x.z != 0.f) { int p = atomicAdd(&edge_cnt[e0+2], 1); if (p < MAXD) edge_nodes[(e0+2)*MAXD+p] = n; c++; }
            if (x.w != 0.f) { int p = atomicAdd(&edge_cnt[e0+3], 1); if (p < MAXD) edge_nodes[(e0+3)*MAXD+p] = n; c++; }
            atomicAdd(&node_cnt[n], c);
        }
    }
}

// ---------------- exclusive scan of node counts (single block) ----------------
__global__ __launch_bounds__(256) void scan_offsets_k(const int* __restrict__ cnt,
                                                      int* __restrict__ off)
{
    __shared__ int part[256];
    const int t = threadIdx.x;
    int s = 0;
    for (int i = 0; i < 64; ++i) s += cnt[t * 64 + i];
    part[t] = s;
    __syncthreads();
    if (t == 0) {
        int run = 0;
        for (int i = 0; i < 256; ++i) { int tmp = part[i]; part[i] = run; run += tmp; }
        off[N_NODES] = run;
    }
    __syncthreads();
    int base = part[t];
    for (int i = 0; i < 64; ++i) { off[t * 64 + i] = base; base += cnt[t * 64 + i]; }
}

// ---------------- fill node->edge CSR ----------------
__global__ __launch_bounds__(256) void fill_csr_k(const int* __restrict__ edge_cnt,
    const int* __restrict__ edge_nodes, const int* __restrict__ node_off,
    int* __restrict__ node_cur, int* __restrict__ node_edges)
{
    int idx = blockIdx.x * blockDim.x + threadIdx.x;
    if (idx >= N_EDGES * MAXD) return;
    int e = idx >> 5, j = idx & 31;
    if (j < edge_cnt[e]) {
        int n = edge_nodes[idx];
        int p = atomicAdd(&node_cur[n], 1);
        node_edges[node_off[n] + p] = e;
    }
}

// ---------------- per-edge attention bias: ea = (sum edge_feat) @ We + be ----------------
__global__ __launch_bounds__(64) void edge_attn_k(const int* __restrict__ edge_cnt,
    const int* __restrict__ edge_nodes, const float* __restrict__ edge_feat,
    const float* __restrict__ We, const float* __restrict__ be, float* __restrict__ ea)
{
    const int e = blockIdx.x;
    const int l = threadIdx.x;      // dim 0..63
    const int cnt = edge_cnt[e];
    float he = 0.f;
    for (int j = 0; j < cnt; ++j) {
        int n = edge_nodes[e * MAXD + j];
        he += edge_feat[n * 64 + l];
    }
    float p[8];
#pragma unroll
    for (int h = 0; h < 8; ++h) p[h] = he * We[l * 8 + h];
#pragma unroll
    for (int off = 32; off >= 1; off >>= 1) {
#pragma unroll
        for (int h = 0; h < 8; ++h) p[h] += __shfl_xor(p[h], off);
    }
    if (l == 0) {
#pragma unroll
        for (int h = 0; h < 8; ++h) ea[e * 8 + h] = p[h] + be[h];
    }
}

// ---------------- per-(node,head) softmax stats: m and 1/(Z+eps) ----------------
__global__ __launch_bounds__(256) void mz_k(const int* __restrict__ node_off,
    const int* __restrict__ node_edges, const float* __restrict__ ea,
    float* __restrict__ m_out, float* __restrict__ s_out)
{
    int t = blockIdx.x * blockDim.x + threadIdx.x;
    if (t >= N_NODES * 8) return;
    int n = t >> 3, h = t & 7;
    int b = node_off[n], eend = node_off[n + 1];
    float m = -INFINITY;
    for (int i = b; i < eend; ++i) m = fmaxf(m, ea[node_edges[i] * 8 + h]);
    float z = 0.f;
    for (int i = b; i < eend; ++i) z += __expf(ea[node_edges[i] * 8 + h] - m);
    m_out[t] = m;
    s_out[t] = 1.0f / (z + 1e-10f);
}

// ---------------- per-edge message: msg[e,c] = sum_j attn(e,n_j,h) * vsrc[n_j,c] ----------------
__global__ __launch_bounds__(128) void msg_k(const int* __restrict__ edge_cnt,
    const int* __restrict__ edge_nodes, const float* __restrict__ ea,
    const float* __restrict__ m_arr, const float* __restrict__ s_arr,
    const float* __restrict__ vsrc, float* __restrict__ msg)
{
    const int e = blockIdx.x;
    const int c = threadIdx.x;        // 0..127
    const int h = c >> 4;
    const int cnt = edge_cnt[e];
    const float ea_h = ea[e * 8 + h];
    float acc = 0.f;
    for (int j = 0; j < cnt; ++j) {
        int n = edge_nodes[e * MAXD + j];
        float w = __expf(ea_h - m_arr[n * 8 + h]) * s_arr[n * 8 + h];
        acc += w * vsrc[n * 128 + c];
    }
    msg[e * 128 + c] = acc;
}

// ---------------- per-node aggregation: rst[n,c] = sum_{e in n} msg[e,c] ----------------
__global__ __launch_bounds__(128) void rst_k(const int* __restrict__ node_off,
    const int* __restrict__ node_edges, const float* __restrict__ msg,
    float* __restrict__ rst)
{
    const int n = blockIdx.x;
    const int c = threadIdx.x;
    int b = node_off[n], eend = node_off[n + 1];
    float acc = 0.f;
    for (int i = b; i < eend; ++i) acc += msg[node_edges[i] * 128 + c];
    rst[n * 128 + c] = acc;
}

// ---------------- generic f32 GEMM: C = A[M,K] @ B[K,N] (+bias)(+relu)(+resid) ----------------
template <int K, int N, bool RELU, bool BIAS, bool RESID>
__global__ __launch_bounds__(256) void gemm_rows32_k(const float* __restrict__ A,
    const float* __restrict__ B, const float* __restrict__ bias,
    const float* __restrict__ resid, float* __restrict__ C)
{
    constexpr int KT  = 64;
    constexpr int CPT = N / 16;       // cols per thread
    __shared__ float Bs[KT][N];
    __shared__ float As[32][KT];
    const int tid  = threadIdx.x;
    const int row0 = blockIdx.x * 32;
    const int r    = tid >> 4;            // 0..15, owns rows r and r+16
    const int c0   = (tid & 15) * CPT;

    float acc[2][CPT];
#pragma unroll
    for (int i = 0; i < 2; ++i)
#pragma unroll
        for (int j = 0; j < CPT; ++j) acc[i][j] = 0.f;

    for (int kt = 0; kt < K; kt += KT) {
        constexpr int BVEC = KT * N / 4;
        for (int v4 = tid; v4 < BVEC; v4 += 256) {
            int kk = v4 / (N / 4);
            int cc = (v4 % (N / 4)) * 4;
            *(float4*)&Bs[kk][cc] = *(const float4*)&B[(kt + kk) * N + cc];
        }
        for (int v4 = tid; v4 < 512; v4 += 256) {
            int rr = v4 >> 4;
            int cc = (v4 & 15) * 4;
            *(float4*)&As[rr][cc] = *(const float4*)&A[(row0 + rr) * K + kt + cc];
        }
        __syncthreads();
#pragma unroll
        for (int k = 0; k < KT; ++k) {
            float a0 = As[r][k];
            float a1 = As[r + 16][k];
#pragma unroll
            for (int j = 0; j < CPT; ++j) {
                float b = Bs[k][c0 + j];
                acc[0][j] = fmaf(a0, b, acc[0][j]);
                acc[1][j] = fmaf(a1, b, acc[1][j]);
            }
        }
        __syncthreads();
    }
#pragma unroll
    for (int i = 0; i < 2; ++i) {
        int row = row0 + r + i * 16;
#pragma unroll
        for (int j = 0; j < CPT; ++j) {
            int col = c0 + j;
            float x = acc[i][j];
            if constexpr (BIAS)  x += bias[col];
            if constexpr (RELU)  x = fmaxf(x, 0.f);
            if constexpr (RESID) x += resid[row * N + col];
            C[row * N + col] = x;
        }
    }
}

extern "C" void kernel_launch(void* const* d_in, const int* in_sizes, int n_in,
                              void* d_out, int out_size, void* d_ws, size_t ws_size,
                              hipStream_t stream)
{
    const float* q  = (const float*)d_in[0];
    // d_in[1] = k  : mathematically dead (cancels in segment softmax)
    const float* v  = (const float*)d_in[2];
    const float* ef = (const float*)d_in[3];
    const float* H  = (const float*)d_in[4];
    // d_in[5] = Wq, d_in[6] = Wk : dead
    const float* Wv = (const float*)d_in[7];
    const float* We = (const float*)d_in[8];
    const float* be = (const float*)d_in[9];
    const float* Wo = (const float*)d_in[10];
    const float* W1 = (const float*)d_in[11];
    const float* b1 = (const float*)d_in[12];
    const float* W2 = (const float*)d_in[13];
    const float* b2 = (const float*)d_in[14];
    float* out = (float*)d_out;

    char* w = (char*)d_ws;
    auto carve = [&](size_t bytes) -> void* {
        void* p = (void*)w;
        w += (bytes + 255) & ~(size_t)255;
        return p;
    };
    // first three contiguous -> single memset
    int* edge_cnt   = (int*)carve(N_EDGES * 4);            // 32 KB
    int* node_cnt   = (int*)carve(N_NODES * 4);            // 64 KB
    int* node_cur   = (int*)carve(N_NODES * 4);            // 64 KB
    size_t zero_bytes = (size_t)(w - (char*)d_ws);
    int* edge_nodes = (int*)carve((size_t)N_EDGES * MAXD * 4);
    int* node_off   = (int*)carve((N_NODES + 1) * 4);
    int* node_edges = (int*)carve((size_t)N_EDGES * MAXD * 4);
    float* ea       = (float*)carve((size_t)N_EDGES * 8 * 4);
    float* m_arr    = (float*)carve((size_t)N_NODES * 8 * 4);
    float* s_arr    = (float*)carve((size_t)N_NODES * 8 * 4);
    float* vsrc     = (float*)carve((size_t)N_NODES * 128 * 4);
    float* msg      = (float*)carve((size_t)N_EDGES * 128 * 4);
    float* rst      = (float*)carve((size_t)N_NODES * 128 * 4);
    float* tbuf     = (float*)carve((size_t)N_NODES * 256 * 4);
    (void)ws_size; (void)in_sizes; (void)n_in; (void)out_size;

    hipMemsetAsync(d_ws, 0, zero_bytes, stream);

    scan_H_k<<<4096, 256, 0, stream>>>(H, edge_cnt, edge_nodes, node_cnt);
    scan_offsets_k<<<1, 256, 0, stream>>>(node_cnt, node_off);
    fill_csr_k<<<(N_EDGES * MAXD) / 256, 256, 0, stream>>>(edge_cnt, edge_nodes, node_off,
                                                           node_cur, node_edges);
    edge_attn_k<<<N_EDGES, 64, 0, stream>>>(edge_cnt, edge_nodes, ef, We, be, ea);
    mz_k<<<(N_NODES * 8) / 256, 256, 0, stream>>>(node_off, node_edges, ea, m_arr, s_arr);

    // vsrc = v @ Wv
    gemm_rows32_k<128, 128, false, false, false><<<N_NODES / 32, 256, 0, stream>>>(
        v, Wv, nullptr, nullptr, vsrc);

    msg_k<<<N_EDGES, 128, 0, stream>>>(edge_cnt, edge_nodes, ea, m_arr, s_arr, vsrc, msg);
    rst_k<<<N_NODES, 128, 0, stream>>>(node_off, node_edges, msg, rst);

    // h = rst @ Wo + q   (stored in d_out)
    gemm_rows32_k<128, 128, false, false, true><<<N_NODES / 32, 256, 0, stream>>>(
        rst, Wo, nullptr, q, out);
    // t = relu(h @ W1 + b1)
    gemm_rows32_k<128, 256, true, true, false><<<N_NODES / 32, 256, 0, stream>>>(
        out, W1, b1, nullptr, tbuf);
    // out = h + t @ W2 + b2
    gemm_rows32_k<256, 128, false, true, true><<<N_NODES / 32, 256, 0, stream>>>(
        tbuf, W2, b2, out, out);
}

// Round 2
// 317.959 us; speedup vs baseline: 1.1212x; 1.1212x over previous
//
#include <hip/hip_runtime.h>

#define N_NODES 16384
#define N_EDGES 8192
#define MAXD 32

// ---------------- shared GEMM body: C[32 rows] = A @ B (+bias)(+relu)(+resid) ----------------
template <int K, int N, int KT, bool RELU, bool BIAS, bool RESID>
__device__ __forceinline__ void gemm_body(const float* __restrict__ A,
    const float* __restrict__ B, const float* __restrict__ bias,
    const float* __restrict__ resid, float* __restrict__ C, int blk)
{
    constexpr int CPT = N / 16;
    __shared__ float Bs[KT][N];
    __shared__ float As[32][KT];
    const int tid  = threadIdx.x;
    const int row0 = blk * 32;
    const int r    = tid >> 4;
    const int c0   = (tid & 15) * CPT;

    float acc[2][CPT];
#pragma unroll
    for (int i = 0; i < 2; ++i)
#pragma unroll
        for (int j = 0; j < CPT; ++j) acc[i][j] = 0.f;

    for (int kt = 0; kt < K; kt += KT) {
        for (int u = tid; u < KT * N / 4; u += 256) {
            int kk = u / (N / 4);
            int cc = (u % (N / 4)) * 4;
            *(float4*)&Bs[kk][cc] = *(const float4*)&B[(kt + kk) * N + cc];
        }
        for (int u = tid; u < 32 * KT / 4; u += 256) {
            int rr = u / (KT / 4);
            int cc = (u % (KT / 4)) * 4;
            *(float4*)&As[rr][cc] = *(const float4*)&A[(row0 + rr) * K + kt + cc];
        }
        __syncthreads();
#pragma unroll
        for (int k = 0; k < KT; ++k) {
            float a0 = As[r][k];
            float a1 = As[r + 16][k];
#pragma unroll
            for (int j = 0; j < CPT; ++j) {
                float b = Bs[k][c0 + j];
                acc[0][j] = fmaf(a0, b, acc[0][j]);
                acc[1][j] = fmaf(a1, b, acc[1][j]);
            }
        }
        __syncthreads();
    }
#pragma unroll
    for (int i = 0; i < 2; ++i) {
        int row = row0 + r + i * 16;
#pragma unroll
        for (int j = 0; j < CPT; ++j) {
            int col = c0 + j;
            float x = acc[i][j];
            if constexpr (BIAS)  x += bias[col];
            if constexpr (RELU)  x = fmaxf(x, 0.f);
            if constexpr (RESID) x += resid[row * N + col];
            C[row * N + col] = x;
        }
    }
}

// ---------------- phase 1 (fused): vsrc GEMM ∥ pe projection ∥ H scan ----------------
// blocks [0,512): vsrc = v @ Wv        (compute hides under the BW-bound scan)
// blocks [512,1024): pe[n,h] = ef[n,:] @ We[:,h]
// blocks [1024,5120): scan dense H -> edge member lists + node counts
__global__ __launch_bounds__(256) void phase1_k(
    const float* __restrict__ v, const float* __restrict__ Wv,
    const float* __restrict__ ef, const float* __restrict__ We,
    const float* __restrict__ H,
    int* __restrict__ edge_cnt, int* __restrict__ edge_nodes, int* __restrict__ node_cnt,
    float* __restrict__ vsrc, float* __restrict__ pe)
{
    const int b = blockIdx.x;
    if (b < 512) {
        gemm_body<128, 128, 32, false, false, false>(v, Wv, nullptr, nullptr, vsrc, b);
    } else if (b < 1024) {
        int g = (b - 512) * 256 + threadIdx.x;   // (n,h)
        int n = g >> 3, h = g & 7;
        const float4* ef4 = (const float4*)ef + n * 16;
        float p = 0.f;
#pragma unroll
        for (int d4 = 0; d4 < 16; ++d4) {
            float4 x = ef4[d4];
            p += x.x * We[(d4 * 4 + 0) * 8 + h] + x.y * We[(d4 * 4 + 1) * 8 + h]
               + x.z * We[(d4 * 4 + 2) * 8 + h] + x.w * We[(d4 * 4 + 3) * 8 + h];
        }
        pe[g] = p;
    } else {
        const unsigned total4 = (unsigned)N_NODES * (N_EDGES / 4);
        for (unsigned i = (unsigned)(b - 1024) * 256u + threadIdx.x; i < total4;
             i += 4096u * 256u) {
            float4 x = reinterpret_cast<const float4*>(H)[i];
            if (x.x != 0.f || x.y != 0.f || x.z != 0.f || x.w != 0.f) {
                unsigned base = i * 4u;
                int n  = (int)(base >> 13);
                int e0 = (int)(base & (N_EDGES - 1));
                int c = 0;
                if (x.x != 0.f) { int p = atomicAdd(&edge_cnt[e0+0], 1); if (p < MAXD) edge_nodes[(e0+0)*MAXD+p] = n; c++; }
                if (x.y != 0.f) { int p = atomicAdd(&edge_cnt[e0+1], 1); if (p < MAXD) edge_nodes[(e0+1)*MAXD+p] = n; c++; }
                if (x.z != 0.f) { int p = atomicAdd(&edge_cnt[e0+2], 1); if (p < MAXD) edge_nodes[(e0+2)*MAXD+p] = n; c++; }
                if (x.w != 0.f) { int p = atomicAdd(&edge_cnt[e0+3], 1); if (p < MAXD) edge_nodes[(e0+3)*MAXD+p] = n; c++; }
                atomicAdd(&node_cnt[n], c);
            }
        }
    }
}

// ---------------- exclusive scan of node counts (single block, shfl-parallel) ----------------
__global__ __launch_bounds__(256) void scan_offsets_k(const int* __restrict__ cnt,
                                                      int* __restrict__ off)
{
    __shared__ int wsum[4];
    const int t = threadIdx.x;
    int s = 0;
#pragma unroll
    for (int i = 0; i < 16; ++i) {
        int4 x = ((const int4*)cnt)[t * 16 + i];
        s += x.x + x.y + x.z + x.w;
    }
    const int lane = t & 63, w = t >> 6;
    int sc = s;
#pragma unroll
    for (int o = 1; o < 64; o <<= 1) {
        int u = __shfl_up(sc, o);
        if (lane >= o) sc += u;
    }
    if (lane == 63) wsum[w] = sc;
    __syncthreads();
    int wb = 0;
    for (int i = 0; i < w; ++i) wb += wsum[i];
    int run = wb + sc - s;                 // exclusive prefix of this thread's 64-chunk
    for (int i = 0; i < 64; ++i) { off[t * 64 + i] = run; run += cnt[t * 64 + i]; }
    if (t == 255) off[N_NODES] = run;
}

// ---------------- phase 3 (fused): fill node->edge CSR ∥ edge attn bias ----------------
// blocks [0,1024): CSR fill; blocks [1024,1280): ea[e,h] = sum_j pe[n_j,h] + be[h]
__global__ __launch_bounds__(256) void phase3_k(const int* __restrict__ edge_cnt,
    const int* __restrict__ edge_nodes, const int* __restrict__ node_off,
    int* __restrict__ node_cur, int* __restrict__ node_edges,
    const float* __restrict__ pe, const float* __restrict__ be, float* __restrict__ ea)
{
    const int b = blockIdx.x;
    if (b < 1024) {
        int idx = b * 256 + threadIdx.x;
        int e = idx >> 5, j = idx & 31;
        if (j < edge_cnt[e]) {
            int n = edge_nodes[idx];
            int p = atomicAdd(&node_cur[n], 1);
            node_edges[node_off[n] + p] = e;
        }
    } else {
        int g = (b - 1024) * 256 + threadIdx.x;  // (e,h)
        int e = g >> 3, h = g & 7;
        int cnt = edge_cnt[e];
        float s = be[h];
        for (int j = 0; j < cnt; ++j) s += pe[edge_nodes[e * MAXD + j] * 8 + h];
        ea[g] = s;
    }
}

// ---------------- per-(node,head) softmax stats ----------------
__global__ __launch_bounds__(256) void mz_k(const int* __restrict__ node_off,
    const int* __restrict__ node_edges, const float* __restrict__ ea,
    float* __restrict__ m_out, float* __restrict__ s_out)
{
    int t = blockIdx.x * blockDim.x + threadIdx.x;
    if (t >= N_NODES * 8) return;
    int n = t >> 3, h = t & 7;
    int b = node_off[n], eend = node_off[n + 1];
    float m = -INFINITY;
    for (int i = b; i < eend; ++i) m = fmaxf(m, ea[node_edges[i] * 8 + h]);
    float z = 0.f;
    for (int i = b; i < eend; ++i) z += __expf(ea[node_edges[i] * 8 + h] - m);
    m_out[t] = m;
    s_out[t] = 1.0f / (z + 1e-10f);
}

// ---------------- per-edge message (float4 lanes) ----------------
__global__ __launch_bounds__(256) void msg_k(const int* __restrict__ edge_cnt,
    const int* __restrict__ edge_nodes, const float* __restrict__ ea,
    const float* __restrict__ m_arr, const float* __restrict__ s_arr,
    const float* __restrict__ vsrc, float* __restrict__ msg)
{
    int g = blockIdx.x * 256 + threadIdx.x;     // [0, 262144)
    int e = g >> 5, c4 = g & 31, h = c4 >> 2;
    int cnt = edge_cnt[e];
    float ea_h = ea[e * 8 + h];
    float4 acc = {0.f, 0.f, 0.f, 0.f};
    const float4* v4 = (const float4*)vsrc;
    for (int j = 0; j < cnt; ++j) {
        int n = edge_nodes[e * MAXD + j];
        float w = __expf(ea_h - m_arr[n * 8 + h]) * s_arr[n * 8 + h];
        float4 x = v4[n * 32 + c4];
        acc.x += w * x.x; acc.y += w * x.y; acc.z += w * x.z; acc.w += w * x.w;
    }
    ((float4*)msg)[g] = acc;
}

// ---------------- per-node aggregation (float4 lanes) ----------------
__global__ __launch_bounds__(256) void rst_k(const int* __restrict__ node_off,
    const int* __restrict__ node_edges, const float* __restrict__ msg,
    float* __restrict__ rst)
{
    int g = blockIdx.x * 256 + threadIdx.x;     // [0, 524288)
    int n = g >> 5, c4 = g & 31;
    int b = node_off[n], eend = node_off[n + 1];
    float4 acc = {0.f, 0.f, 0.f, 0.f};
    const float4* m4 = (const float4*)msg;
    for (int i = b; i < eend; ++i) {
        float4 x = m4[node_edges[i] * 32 + c4];
        acc.x += x.x; acc.y += x.y; acc.z += x.z; acc.w += x.w;
    }
    ((float4*)rst)[g] = acc;
}

// ---------------- standalone GEMM wrapper (Wo epilogue) ----------------
template <int K, int N, int KT, bool RELU, bool BIAS, bool RESID>
__global__ __launch_bounds__(256) void gemm_k(const float* __restrict__ A,
    const float* __restrict__ B, const float* __restrict__ bias,
    const float* __restrict__ resid, float* __restrict__ C)
{
    gemm_body<K, N, KT, RELU, BIAS, RESID>(A, B, bias, resid, C, blockIdx.x);
}

// ---------------- fused FFN: out = h + relu(h@W1+b1)@W2 + b2 (in place, h = out) ----------------
__global__ __launch_bounds__(256) void ffn_k(const float* __restrict__ W1,
    const float* __restrict__ b1, const float* __restrict__ W2,
    const float* __restrict__ b2, float* __restrict__ io)
{
    __shared__ char lds[73728];                       // 72 KB
    float (*As)[64]   = (float(*)[64])lds;            // [0, 8K)
    float (*B1s)[256] = (float(*)[256])(lds + 8192);  // [8K, 72K)
    float (*Ts)[256]  = (float(*)[256])lds;           // [0, 32K)   (phase B)
    float (*B2s)[128] = (float(*)[128])(lds + 32768); // [32K, 64K) (phase B)

    const int tid = threadIdx.x;
    const int row0 = blockIdx.x * 32;
    const int r = tid >> 4;
    const int cb = tid & 15;

    // phase A: T = relu(h @ W1 + b1), h rows 32x128, T 32x256
    float acc[2][16];
#pragma unroll
    for (int i = 0; i < 2; ++i)
#pragma unroll
        for (int j = 0; j < 16; ++j) acc[i][j] = 0.f;

    for (int kt = 0; kt < 128; kt += 64) {
        for (int u = tid; u < 4096; u += 256) {       // B1s 64x256
            int kk = u >> 6, cc = (u & 63) * 4;
            *(float4*)&B1s[kk][cc] = *(const float4*)&W1[(kt + kk) * 256 + cc];
        }
        for (int u = tid; u < 512; u += 256) {        // As 32x64
            int rr = u >> 4, cc = (u & 15) * 4;
            *(float4*)&As[rr][cc] = *(const float4*)&io[(row0 + rr) * 128 + kt + cc];
        }
        __syncthreads();
#pragma unroll
        for (int k = 0; k < 64; ++k) {
            float a0 = As[r][k], a1 = As[r + 16][k];
#pragma unroll
            for (int j = 0; j < 16; ++j) {
                float b = B1s[k][cb * 16 + j];
                acc[0][j] = fmaf(a0, b, acc[0][j]);
                acc[1][j] = fmaf(a1, b, acc[1][j]);
            }
        }
        __syncthreads();
    }
    // write T (relu + bias) into Ts; As/B1s-head are dead after the last sync
#pragma unroll
    for (int i = 0; i < 2; ++i)
#pragma unroll
        for (int j = 0; j < 16; ++j) {
            int col = cb * 16 + j;
            Ts[r + i * 16][col] = fmaxf(acc[i][j] + b1[col], 0.f);
        }

    // phase B: C = T @ W2 (256 -> 128), += h + b2
    float acc2[2][8];
#pragma unroll
    for (int i = 0; i < 2; ++i)
#pragma unroll
        for (int j = 0; j < 8; ++j) acc2[i][j] = 0.f;

    for (int kt = 0; kt < 256; kt += 64) {
        for (int u = tid; u < 2048; u += 256) {       // B2s 64x128
            int kk = u >> 5, cc = (u & 31) * 4;
            *(float4*)&B2s[kk][cc] = *(const float4*)&W2[(kt + kk) * 128 + cc];
        }
        __syncthreads();                               // also orders Ts writes before reads
#pragma unroll
        for (int k = 0; k < 64; ++k) {
            float a0 = Ts[r][kt + k], a1 = Ts[r + 16][kt + k];
#pragma unroll
            for (int j = 0; j < 8; ++j) {
                float b = B2s[k][cb * 8 + j];
                acc2[0][j] = fmaf(a0, b, acc2[0][j]);
                acc2[1][j] = fmaf(a1, b, acc2[1][j]);
            }
        }
        __syncthreads();
    }
#pragma unroll
    for (int i = 0; i < 2; ++i) {
        int row = row0 + r + i * 16;
#pragma unroll
        for (int j = 0; j < 8; ++j) {
            int col = cb * 8 + j;
            io[row * 128 + col] = io[row * 128 + col] + acc2[i][j] + b2[col];
        }
    }
}

extern "C" void kernel_launch(void* const* d_in, const int* in_sizes, int n_in,
                              void* d_out, int out_size, void* d_ws, size_t ws_size,
                              hipStream_t stream)
{
    const float* q  = (const float*)d_in[0];
    // d_in[1] = k  : dead (per-node qk dot cancels in the segment softmax)
    const float* v  = (const float*)d_in[2];
    const float* ef = (const float*)d_in[3];
    const float* H  = (const float*)d_in[4];
    // d_in[5] = Wq, d_in[6] = Wk : dead
    const float* Wv = (const float*)d_in[7];
    const float* We = (const float*)d_in[8];
    const float* be = (const float*)d_in[9];
    const float* Wo = (const float*)d_in[10];
    const float* W1 = (const float*)d_in[11];
    const float* b1 = (const float*)d_in[12];
    const float* W2 = (const float*)d_in[13];
    const float* b2 = (const float*)d_in[14];
    float* out = (float*)d_out;

    char* w = (char*)d_ws;
    auto carve = [&](size_t bytes) -> void* {
        void* p = (void*)w;
        w += (bytes + 255) & ~(size_t)255;
        return p;
    };
    int* edge_cnt   = (int*)carve(N_EDGES * 4);
    int* node_cnt   = (int*)carve(N_NODES * 4);
    int* node_cur   = (int*)carve(N_NODES * 4);
    size_t zero_bytes = (size_t)(w - (char*)d_ws);
    int* edge_nodes = (int*)carve((size_t)N_EDGES * MAXD * 4);
    int* node_off   = (int*)carve((N_NODES + 1) * 4);
    int* node_edges = (int*)carve((size_t)N_EDGES * MAXD * 4);
    float* ea       = (float*)carve((size_t)N_EDGES * 8 * 4);
    float* m_arr    = (float*)carve((size_t)N_NODES * 8 * 4);
    float* s_arr    = (float*)carve((size_t)N_NODES * 8 * 4);
    float* pe       = (float*)carve((size_t)N_NODES * 8 * 4);
    float* vsrc     = (float*)carve((size_t)N_NODES * 128 * 4);
    float* msg      = (float*)carve((size_t)N_EDGES * 128 * 4);
    float* rst      = (float*)carve((size_t)N_NODES * 128 * 4);
    (void)ws_size; (void)in_sizes; (void)n_in; (void)out_size;

    hipMemsetAsync(d_ws, 0, zero_bytes, stream);

    phase1_k<<<5120, 256, 0, stream>>>(v, Wv, ef, We, H,
                                       edge_cnt, edge_nodes, node_cnt, vsrc, pe);
    scan_offsets_k<<<1, 256, 0, stream>>>(node_cnt, node_off);
    phase3_k<<<1280, 256, 0, stream>>>(edge_cnt, edge_nodes, node_off,
                                       node_cur, node_edges, pe, be, ea);
    mz_k<<<(N_NODES * 8) / 256, 256, 0, stream>>>(node_off, node_edges, ea, m_arr, s_arr);
    msg_k<<<(N_EDGES * 32) / 256, 256, 0, stream>>>(edge_cnt, edge_nodes, ea,
                                                    m_arr, s_arr, vsrc, msg);
    rst_k<<<(N_NODES * 32) / 256, 256, 0, stream>>>(node_off, node_edges, msg, rst);

    gemm_k<128, 128, 64, false, false, true><<<N_NODES / 32, 256, 0, stream>>>(
        rst, Wo, nullptr, q, out);
    ffn_k<<<N_NODES / 32, 256, 0, stream>>>(W1, b1, W2, b2, out);
}

// Round 3
// 300.108 us; speedup vs baseline: 1.1878x; 1.0595x over previous
//
#include <hip/hip_runtime.h>

#define N_NODES 16384
#define N_EDGES 8192
#define MAXD 32

// ---------------- shared GEMM body: C[32 rows] = A @ B ----------------
template <int K, int N, int KT, bool RELU, bool BIAS, bool RESID>
__device__ __forceinline__ void gemm_body(const float* __restrict__ A,
    const float* __restrict__ B, const float* __restrict__ bias,
    const float* __restrict__ resid, float* __restrict__ C, int blk)
{
    constexpr int CPT = N / 16;
    __shared__ float Bs[KT][N];
    __shared__ float As[32][KT];
    const int tid  = threadIdx.x;
    const int row0 = blk * 32;
    const int r    = tid >> 4;
    const int c0   = (tid & 15) * CPT;

    float acc[2][CPT];
#pragma unroll
    for (int i = 0; i < 2; ++i)
#pragma unroll
        for (int j = 0; j < CPT; ++j) acc[i][j] = 0.f;

    for (int kt = 0; kt < K; kt += KT) {
        for (int u = tid; u < KT * N / 4; u += 256) {
            int kk = u / (N / 4);
            int cc = (u % (N / 4)) * 4;
            *(float4*)&Bs[kk][cc] = *(const float4*)&B[(kt + kk) * N + cc];
        }
        for (int u = tid; u < 32 * KT / 4; u += 256) {
            int rr = u / (KT / 4);
            int cc = (u % (KT / 4)) * 4;
            *(float4*)&As[rr][cc] = *(const float4*)&A[(row0 + rr) * K + kt + cc];
        }
        __syncthreads();
#pragma unroll
        for (int k = 0; k < KT; ++k) {
            float a0 = As[r][k];
            float a1 = As[r + 16][k];
#pragma unroll
            for (int j = 0; j < CPT; ++j) {
                float b = Bs[k][c0 + j];
                acc[0][j] = fmaf(a0, b, acc[0][j]);
                acc[1][j] = fmaf(a1, b, acc[1][j]);
            }
        }
        __syncthreads();
    }
#pragma unroll
    for (int i = 0; i < 2; ++i) {
        int row = row0 + r + i * 16;
#pragma unroll
        for (int j = 0; j < CPT; ++j) {
            int col = c0 + j;
            float x = acc[i][j];
            if constexpr (BIAS)  x += bias[col];
            if constexpr (RELU)  x = fmaxf(x, 0.f);
            if constexpr (RESID) x += resid[row * N + col];
            C[row * N + col] = x;
        }
    }
}

template <int K, int N, int KT, bool RELU, bool BIAS, bool RESID>
__global__ __launch_bounds__(256) void gemm_k(const float* __restrict__ A,
    const float* __restrict__ B, const float* __restrict__ bias,
    const float* __restrict__ resid, float* __restrict__ C)
{
    gemm_body<K, N, KT, RELU, BIAS, RESID>(A, B, bias, resid, C, blockIdx.x);
}

// ---------------- phase 1 (fused): vsrc GEMM ∥ pe projection ∥ H scan ----------------
__global__ __launch_bounds__(256) void phase1_k(
    const float* __restrict__ v, const float* __restrict__ Wv,
    const float* __restrict__ ef, const float* __restrict__ We,
    const float* __restrict__ H,
    int* __restrict__ edge_cnt, int* __restrict__ edge_nodes, int* __restrict__ node_cnt,
    float* __restrict__ vsrc, float* __restrict__ pe)
{
    const int b = blockIdx.x;
    if (b < 512) {
        gemm_body<128, 128, 32, false, false, false>(v, Wv, nullptr, nullptr, vsrc, b);
    } else if (b < 1024) {
        int g = (b - 512) * 256 + threadIdx.x;   // (n,h)
        int n = g >> 3, h = g & 7;
        const float4* ef4 = (const float4*)ef + n * 16;
        float p = 0.f;
#pragma unroll
        for (int d4 = 0; d4 < 16; ++d4) {
            float4 x = ef4[d4];
            p += x.x * We[(d4 * 4 + 0) * 8 + h] + x.y * We[(d4 * 4 + 1) * 8 + h]
               + x.z * We[(d4 * 4 + 2) * 8 + h] + x.w * We[(d4 * 4 + 3) * 8 + h];
        }
        pe[g] = p;
    } else {
        const unsigned total4 = (unsigned)N_NODES * (N_EDGES / 4);
        for (unsigned i = (unsigned)(b - 1024) * 256u + threadIdx.x; i < total4;
             i += 4096u * 256u) {
            float4 x = reinterpret_cast<const float4*>(H)[i];
            if (x.x != 0.f || x.y != 0.f || x.z != 0.f || x.w != 0.f) {
                unsigned base = i * 4u;
                int n  = (int)(base >> 13);
                int e0 = (int)(base & (N_EDGES - 1));
                int c = 0;
                if (x.x != 0.f) { int p = atomicAdd(&edge_cnt[e0+0], 1); if (p < MAXD) edge_nodes[(e0+0)*MAXD+p] = n; c++; }
                if (x.y != 0.f) { int p = atomicAdd(&edge_cnt[e0+1], 1); if (p < MAXD) edge_nodes[(e0+1)*MAXD+p] = n; c++; }
                if (x.z != 0.f) { int p = atomicAdd(&edge_cnt[e0+2], 1); if (p < MAXD) edge_nodes[(e0+2)*MAXD+p] = n; c++; }
                if (x.w != 0.f) { int p = atomicAdd(&edge_cnt[e0+3], 1); if (p < MAXD) edge_nodes[(e0+3)*MAXD+p] = n; c++; }
                atomicAdd(&node_cnt[n], c);
            }
        }
    }
}

// ---------------- exclusive scan of node counts (1 block x 1024) ----------------
__global__ __launch_bounds__(1024) void scan_offsets_k(const int* __restrict__ cnt,
                                                       int* __restrict__ off)
{
    __shared__ int wsum[16];
    const int t = threadIdx.x;      // each thread owns 16 nodes
    int vals[16];
#pragma unroll
    for (int i = 0; i < 4; ++i) {
        int4 x = ((const int4*)cnt)[t * 4 + i];
        vals[i * 4 + 0] = x.x; vals[i * 4 + 1] = x.y;
        vals[i * 4 + 2] = x.z; vals[i * 4 + 3] = x.w;
    }
    int s = 0;
#pragma unroll
    for (int i = 0; i < 16; ++i) s += vals[i];
    const int lane = t & 63, w = t >> 6;
    int sc = s;
#pragma unroll
    for (int o = 1; o < 64; o <<= 1) {
        int u = __shfl_up(sc, o);
        if (lane >= o) sc += u;
    }
    if (lane == 63) wsum[w] = sc;
    __syncthreads();
    int wb = 0;
    for (int i = 0; i < w; ++i) wb += wsum[i];
    int run = wb + sc - s;
#pragma unroll
    for (int i = 0; i < 16; ++i) { off[t * 16 + i] = run; run += vals[i]; }
    if (t == 1023) off[N_NODES] = run;
}

// ---------------- phase 3 (fused): fill node->edge CSR ∥ eexp = exp(edge bias) ----------------
__global__ __launch_bounds__(256) void phase3_k(const int* __restrict__ edge_cnt,
    const int* __restrict__ edge_nodes, const int* __restrict__ node_off,
    int* __restrict__ node_cur, int* __restrict__ node_edges,
    const float* __restrict__ pe, const float* __restrict__ be, float* __restrict__ eexp)
{
    const int b = blockIdx.x;
    if (b < 1024) {
        int idx = b * 256 + threadIdx.x;
        int e = idx >> 5, j = idx & 31;
        if (j < edge_cnt[e]) {
            int n = edge_nodes[idx];
            int p = atomicAdd(&node_cur[n], 1);
            node_edges[node_off[n] + p] = e;
        }
    } else {
        int g = (b - 1024) * 256 + threadIdx.x;  // (e,h) in [0, 65536)
        int e = g >> 3, h = g & 7;
        int cnt = edge_cnt[e];
        float s = be[h];
        for (int j = 0; j < cnt; ++j) s += pe[edge_nodes[e * MAXD + j] * 8 + h];
        eexp[g] = __expf(s);     // softmax shift-invariant; |s| small -> safe
    }
}

// ---------------- per-(node,head) inverse partition: s = 1/(sum eexp + eps) ----------------
__global__ __launch_bounds__(256) void z_k(const int* __restrict__ node_off,
    const int* __restrict__ node_edges, const float* __restrict__ eexp,
    float* __restrict__ s_out)
{
    int t = blockIdx.x * blockDim.x + threadIdx.x;
    if (t >= N_NODES * 8) return;
    int n = t >> 3, h = t & 7;
    int b = node_off[n], eend = node_off[n + 1];
    float z = 0.f;
    for (int i = b; i < eend; ++i) z += eexp[node_edges[i] * 8 + h];
    s_out[t] = 1.0f / (z + 1e-10f);
}

// ---------------- per-edge message: msg[e,c] = eexp[e,h] * sum_j s[n_j,h]*vsrc[n_j,c] ----------------
__global__ __launch_bounds__(256) void msg_k(const int* __restrict__ edge_cnt,
    const int* __restrict__ edge_nodes, const float* __restrict__ eexp,
    const float* __restrict__ s_arr, const float* __restrict__ vsrc,
    float* __restrict__ msg)
{
    int g = blockIdx.x * 256 + threadIdx.x;     // [0, 262144)
    int e = g >> 5, c4 = g & 31, h = c4 >> 2;
    int cnt = edge_cnt[e];
    float eh = eexp[e * 8 + h];
    float4 acc = {0.f, 0.f, 0.f, 0.f};
    const float4* v4 = (const float4*)vsrc;
    for (int j = 0; j < cnt; ++j) {
        int n = edge_nodes[e * MAXD + j];
        float t = s_arr[n * 8 + h];
        float4 x = v4[n * 32 + c4];
        acc.x = fmaf(t, x.x, acc.x); acc.y = fmaf(t, x.y, acc.y);
        acc.z = fmaf(t, x.z, acc.z); acc.w = fmaf(t, x.w, acc.w);
    }
    acc.x *= eh; acc.y *= eh; acc.z *= eh; acc.w *= eh;
    ((float4*)msg)[g] = acc;
}

// ---------------- final fused: h = q + sum msgo ; out = h + relu(h@W1+b1)@W2 + b2 ----------------
__global__ __launch_bounds__(256) void ffn_agg_k(const float* __restrict__ q,
    const int* __restrict__ node_off, const int* __restrict__ node_edges,
    const float* __restrict__ msgo, const float* __restrict__ W1,
    const float* __restrict__ b1, const float* __restrict__ W2,
    const float* __restrict__ b2, float* __restrict__ out)
{
    __shared__ float Hs[32][128];                     // 16 KB, persistent
    __shared__ char dyn[65536];                       // 64 KB overlay
    float (*B1s)[256] = (float(*)[256])dyn;           // phase A
    float (*Ts)[256]  = (float(*)[256])dyn;           // phase B [0,32K)
    float (*B2s)[128] = (float(*)[128])(dyn + 32768); // phase B [32K,64K)

    const int tid  = threadIdx.x;
    const int row0 = blockIdx.x * 32;

    // ---- aggregate h rows into Hs ----
    {
        int r = tid >> 3, lc = tid & 7;
        int n = row0 + r;
        const float4* q4 = (const float4*)q;
        const float4* m4 = (const float4*)msgo;
        float4 acc[4];
#pragma unroll
        for (int u = 0; u < 4; ++u) acc[u] = q4[n * 32 + lc + 8 * u];
        int b = node_off[n], eend = node_off[n + 1];
        for (int i = b; i < eend; ++i) {
            int e = node_edges[i];
#pragma unroll
            for (int u = 0; u < 4; ++u) {
                float4 x = m4[e * 32 + lc + 8 * u];
                acc[u].x += x.x; acc[u].y += x.y; acc[u].z += x.z; acc[u].w += x.w;
            }
        }
#pragma unroll
        for (int u = 0; u < 4; ++u)
            *(float4*)&Hs[r][(lc + 8 * u) * 4] = acc[u];
    }
    __syncthreads();

    const int r  = tid >> 4;
    const int cb = tid & 15;

    // ---- phase A: T = relu(h @ W1 + b1) ----
    float acc[2][16];
#pragma unroll
    for (int i = 0; i < 2; ++i)
#pragma unroll
        for (int j = 0; j < 16; ++j) acc[i][j] = 0.f;

    for (int kt = 0; kt < 128; kt += 64) {
        for (int u = tid; u < 4096; u += 256) {       // B1s 64x256
            int kk = u >> 6, cc = (u & 63) * 4;
            *(float4*)&B1s[kk][cc] = *(const float4*)&W1[(kt + kk) * 256 + cc];
        }
        __syncthreads();
#pragma unroll
        for (int k = 0; k < 64; ++k) {
            float a0 = Hs[r][kt + k], a1 = Hs[r + 16][kt + k];
#pragma unroll
            for (int j = 0; j < 16; ++j) {
                float b = B1s[k][cb * 16 + j];
                acc[0][j] = fmaf(a0, b, acc[0][j]);
                acc[1][j] = fmaf(a1, b, acc[1][j]);
            }
        }
        __syncthreads();
    }
#pragma unroll
    for (int i = 0; i < 2; ++i)
#pragma unroll
        for (int j = 0; j < 16; ++j) {
            int col = cb * 16 + j;
            Ts[r + i * 16][col] = fmaxf(acc[i][j] + b1[col], 0.f);
        }

    // ---- phase B: out = h + T @ W2 + b2 ----
    float acc2[2][8];
#pragma unroll
    for (int i = 0; i < 2; ++i)
#pragma unroll
        for (int j = 0; j < 8; ++j) acc2[i][j] = 0.f;

    for (int kt = 0; kt < 256; kt += 64) {
        for (int u = tid; u < 2048; u += 256) {       // B2s 64x128
            int kk = u >> 5, cc = (u & 31) * 4;
            *(float4*)&B2s[kk][cc] = *(const float4*)&W2[(kt + kk) * 128 + cc];
        }
        __syncthreads();                              // first one also publishes Ts
#pragma unroll
        for (int k = 0; k < 64; ++k) {
            float a0 = Ts[r][kt + k], a1 = Ts[r + 16][kt + k];
#pragma unroll
            for (int j = 0; j < 8; ++j) {
                float b = B2s[k][cb * 8 + j];
                acc2[0][j] = fmaf(a0, b, acc2[0][j]);
                acc2[1][j] = fmaf(a1, b, acc2[1][j]);
            }
        }
        __syncthreads();
    }
#pragma unroll
    for (int i = 0; i < 2; ++i) {
        int row = row0 + r + i * 16;
#pragma unroll
        for (int j = 0; j < 8; ++j) {
            int col = cb * 8 + j;
            out[row * 128 + col] = Hs[r + i * 16][col] + acc2[i][j] + b2[col];
        }
    }
}

extern "C" void kernel_launch(void* const* d_in, const int* in_sizes, int n_in,
                              void* d_out, int out_size, void* d_ws, size_t ws_size,
                              hipStream_t stream)
{
    const float* q  = (const float*)d_in[0];
    // d_in[1] = k : dead (per-node q·k dot is segment-constant, cancels in softmax)
    const float* v  = (const float*)d_in[2];
    const float* ef = (const float*)d_in[3];
    const float* H  = (const float*)d_in[4];
    // d_in[5] = Wq, d_in[6] = Wk : dead
    const float* Wv = (const float*)d_in[7];
    const float* We = (const float*)d_in[8];
    const float* be = (const float*)d_in[9];
    const float* Wo = (const float*)d_in[10];
    const float* W1 = (const float*)d_in[11];
    const float* b1 = (const float*)d_in[12];
    const float* W2 = (const float*)d_in[13];
    const float* b2 = (const float*)d_in[14];
    float* out = (float*)d_out;

    char* w = (char*)d_ws;
    auto carve = [&](size_t bytes) -> void* {
        void* p = (void*)w;
        w += (bytes + 255) & ~(size_t)255;
        return p;
    };
    int* edge_cnt   = (int*)carve(N_EDGES * 4);
    int* node_cnt   = (int*)carve(N_NODES * 4);
    int* node_cur   = (int*)carve(N_NODES * 4);
    size_t zero_bytes = (size_t)(w - (char*)d_ws);
    int* edge_nodes = (int*)carve((size_t)N_EDGES * MAXD * 4);
    int* node_off   = (int*)carve((N_NODES + 1) * 4);
    int* node_edges = (int*)carve((size_t)N_EDGES * MAXD * 4);
    float* eexp     = (float*)carve((size_t)N_EDGES * 8 * 4);
    float* s_arr    = (float*)carve((size_t)N_NODES * 8 * 4);
    float* pe       = (float*)carve((size_t)N_NODES * 8 * 4);
    float* vsrc     = (float*)carve((size_t)N_NODES * 128 * 4);
    float* msg      = (float*)carve((size_t)N_EDGES * 128 * 4);
    float* msgo     = (float*)carve((size_t)N_EDGES * 128 * 4);
    (void)ws_size; (void)in_sizes; (void)n_in; (void)out_size;

    hipMemsetAsync(d_ws, 0, zero_bytes, stream);

    phase1_k<<<5120, 256, 0, stream>>>(v, Wv, ef, We, H,
                                       edge_cnt, edge_nodes, node_cnt, vsrc, pe);
    scan_offsets_k<<<1, 1024, 0, stream>>>(node_cnt, node_off);
    phase3_k<<<1280, 256, 0, stream>>>(edge_cnt, edge_nodes, node_off,
                                       node_cur, node_edges, pe, be, eexp);
    z_k<<<(N_NODES * 8) / 256, 256, 0, stream>>>(node_off, node_edges, eexp, s_arr);
    msg_k<<<(N_EDGES * 32) / 256, 256, 0, stream>>>(edge_cnt, edge_nodes, eexp,
                                                    s_arr, vsrc, msg);
    // msgo = msg @ Wo   (Wo commutes with the linear aggregation: rst@Wo = H@(msg@Wo))
    gemm_k<128, 128, 64, false, false, false><<<N_EDGES / 32, 256, 0, stream>>>(
        msg, Wo, nullptr, nullptr, msgo);
    ffn_agg_k<<<N_NODES / 32, 256, 0, stream>>>(q, node_off, node_edges, msgo,
                                                W1, b1, W2, b2, out);
}